// Round 1
// baseline (5570.527 us; speedup 1.0000x reference)
//
#include <hip/hip_runtime.h>

// NCA2D: B=16, H=128, W=128, C=16, T=8, HID=128, N_STEPS=64, FC0_IN=49
constexpr int B = 16, H = 128, W = 128, C = 16, T = 8, HID = 128, NSTEPS = 64;
constexpr int FC0_IN = 3 * C + 1; // 49

__global__ __launch_bounds__(256) void nca_step_kernel(
    const float* __restrict__ x_in, float* __restrict__ x_out,
    const float* __restrict__ p0_w, const float* __restrict__ p0_b,
    const float* __restrict__ p1_w, const float* __restrict__ p1_b,
    const float* __restrict__ fc0_w, const float* __restrict__ fc0_b,
    const float* __restrict__ fc1_w,
    const int* __restrict__ acq, float* __restrict__ out, int step)
{
    const int cell = blockIdx.x * 256 + threadIdx.x;   // [0, B*H*W)
    const int w = cell & (W - 1);
    const int h = (cell >> 7) & (H - 1);
    const int b = cell >> 14;

    float y[FC0_IN];
    // conv accumulators start at bias
    #pragma unroll
    for (int c = 0; c < C; ++c) { y[C + c] = p0_b[c]; y[2 * C + c] = p1_b[c]; }

    // 3x3 depthwise convs with reflect padding; center tap also fills y[0..15]
    #pragma unroll
    for (int di = -1; di <= 1; ++di) {
        int hh = h + di;
        hh = (hh < 0) ? 1 : ((hh > H - 1) ? H - 2 : hh);
        #pragma unroll
        for (int dj = -1; dj <= 1; ++dj) {
            int ww = w + dj;
            ww = (ww < 0) ? 1 : ((ww > W - 1) ? W - 2 : ww);
            const int tap = (di + 1) * 3 + (dj + 1);
            const float4* p4 = reinterpret_cast<const float4*>(
                x_in + ((((size_t)b * H + hh) * W + ww) * C));
            float4 q0 = p4[0], q1 = p4[1], q2 = p4[2], q3 = p4[3];
            const float xv[16] = {q0.x, q0.y, q0.z, q0.w, q1.x, q1.y, q1.z, q1.w,
                                  q2.x, q2.y, q2.z, q2.w, q3.x, q3.y, q3.z, q3.w};
            #pragma unroll
            for (int c = 0; c < C; ++c) {
                const float xc = xv[c];
                // weight indices are thread-uniform -> scalar loads
                y[C + c]     = fmaf(xc, p0_w[tap * C + c], y[C + c]);
                y[2 * C + c] = fmaf(xc, p1_w[tap * C + c], y[2 * C + c]);
                if (tap == 4) y[c] = xc;
            }
        }
    }
    y[3 * C] = (float)step * (1.0f / (float)NSTEPS);

    // fc0 (49->128, relu) fused with fc1 (128->16) accumulation
    float acc[C];
    #pragma unroll
    for (int c = 0; c < C; ++c) acc[c] = 0.0f;

    #pragma unroll 2
    for (int k = 0; k < HID; ++k) {
        float hk = fc0_b[k];
        #pragma unroll
        for (int c = 0; c < FC0_IN; ++c)
            hk = fmaf(y[c], fc0_w[k * FC0_IN + c], hk);
        hk = fmaxf(hk, 0.0f);
        #pragma unroll
        for (int c = 0; c < C; ++c)
            acc[c] = fmaf(hk, fc1_w[c * HID + k], acc[c]);
    }

    // sigmoid + residual
    float xo[C];
    #pragma unroll
    for (int c = 0; c < C; ++c) {
        const float s = 1.0f / (1.0f + expf(-acc[c]));
        xo[c] = y[c] + s;
    }

    // store new state (coalesced float4)
    float4* po = reinterpret_cast<float4*>(x_out + (size_t)cell * C);
    po[0] = make_float4(xo[0], xo[1], xo[2], xo[3]);
    po[1] = make_float4(xo[4], xo[5], xo[6], xo[7]);
    po[2] = make_float4(xo[8], xo[9], xo[10], xo[11]);
    po[3] = make_float4(xo[12], xo[13], xo[14], xo[15]);

    // snapshots: data[b,t] = x wherever acquire_at_step[b,t] == step (step>0)
    if (step > 0) {
        #pragma unroll
        for (int t = 0; t < T; ++t) {
            if (acq[b * T + t] == step) {   // b uniform per block -> scalar load
                float4* ps = reinterpret_cast<float4*>(
                    out + ((((size_t)(b * T + t) * H + h) * W + w) * C));
                ps[0] = make_float4(xo[0], xo[1], xo[2], xo[3]);
                ps[1] = make_float4(xo[4], xo[5], xo[6], xo[7]);
                ps[2] = make_float4(xo[8], xo[9], xo[10], xo[11]);
                ps[3] = make_float4(xo[12], xo[13], xo[14], xo[15]);
            }
        }
    }
}

extern "C" void kernel_launch(void* const* d_in, const int* in_sizes, int n_in,
                              void* d_out, int out_size, void* d_ws, size_t ws_size,
                              hipStream_t stream) {
    const float* inputs = (const float*)d_in[0];
    const int*   acq    = (const int*)d_in[1];
    const float* p0_w   = (const float*)d_in[2];
    const float* p0_b   = (const float*)d_in[3];
    const float* p1_w   = (const float*)d_in[4];
    const float* p1_b   = (const float*)d_in[5];
    const float* fc0_w  = (const float*)d_in[6];
    const float* fc0_b  = (const float*)d_in[7];
    const float* fc1_w  = (const float*)d_in[8];
    float* out = (float*)d_out;

    const size_t state_elems = (size_t)B * H * W * C; // 4,194,304 floats = 16 MB
    float* bufA = (float*)d_ws;
    float* bufB = bufA + state_elems;

    // slots with acquire_at_step==0 must stay zero; d_out is poisoned 0xAA
    hipMemsetAsync(d_out, 0, (size_t)out_size * sizeof(float), stream);

    const int n_cells = B * H * W;          // 262144
    const dim3 grid(n_cells / 256), block(256);

    const float* xin = inputs;
    for (int step = 0; step < NSTEPS; ++step) {
        float* xout = (step & 1) ? bufB : bufA;
        nca_step_kernel<<<grid, block, 0, stream>>>(
            xin, xout, p0_w, p0_b, p1_w, p1_b, fc0_w, fc0_b, fc1_w,
            acq, out, step);
        xin = xout;
    }
}

// Round 2
// 5403.954 us; speedup vs baseline: 1.0308x; 1.0308x over previous
//
#include <hip/hip_runtime.h>

// NCA2D: B=16, H=128, W=128, C=16, T=8, HID=128, N_STEPS=64, FC0_IN=49
constexpr int B = 16, H = 128, W = 128, C = 16, T = 8, HID = 128, NSTEPS = 64;
constexpr int FC0_IN = 3 * C + 1; // 49

// block=256 (4 waves); grid=1024 -> at most 16 waves/CU, so request 4 waves/EU:
// this lets the register allocator use up to 128 VGPRs (y[49]+acc[16]+temps
// stay in registers, no spill/remat in the fc0 loop).
__global__ __launch_bounds__(256, 4) void nca_step_kernel(
    const float* __restrict__ x_in, float* __restrict__ x_out,
    const float* __restrict__ p0_w, const float* __restrict__ p0_b,
    const float* __restrict__ p1_w, const float* __restrict__ p1_b,
    const float* __restrict__ fc0_w, const float* __restrict__ fc0_b,
    const float* __restrict__ fc1_w,
    const int* __restrict__ acq, float* __restrict__ out, int step)
{
    const int cell = blockIdx.x * 256 + threadIdx.x;   // [0, B*H*W)
    const int w = cell & (W - 1);
    const int h = (cell >> 7) & (H - 1);
    const int b = cell >> 14;

    float y[FC0_IN];
    // conv accumulators start at bias
    #pragma unroll
    for (int c = 0; c < C; ++c) { y[C + c] = p0_b[c]; y[2 * C + c] = p1_b[c]; }

    // 3x3 depthwise convs with reflect padding; center tap also fills y[0..15]
    #pragma unroll
    for (int di = -1; di <= 1; ++di) {
        int hh = h + di;
        hh = (hh < 0) ? 1 : ((hh > H - 1) ? H - 2 : hh);
        #pragma unroll
        for (int dj = -1; dj <= 1; ++dj) {
            int ww = w + dj;
            ww = (ww < 0) ? 1 : ((ww > W - 1) ? W - 2 : ww);
            const int tap = (di + 1) * 3 + (dj + 1);
            const float4* p4 = reinterpret_cast<const float4*>(
                x_in + ((((size_t)b * H + hh) * W + ww) * C));
            float4 q0 = p4[0], q1 = p4[1], q2 = p4[2], q3 = p4[3];
            const float xv[16] = {q0.x, q0.y, q0.z, q0.w, q1.x, q1.y, q1.z, q1.w,
                                  q2.x, q2.y, q2.z, q2.w, q3.x, q3.y, q3.z, q3.w};
            #pragma unroll
            for (int c = 0; c < C; ++c) {
                const float xc = xv[c];
                // weight indices are thread-uniform -> scalar loads (SGPR operand)
                y[C + c]     = fmaf(xc, p0_w[tap * C + c], y[C + c]);
                y[2 * C + c] = fmaf(xc, p1_w[tap * C + c], y[2 * C + c]);
                if (tap == 4) y[c] = xc;
            }
        }
    }
    y[3 * C] = (float)step * (1.0f / (float)NSTEPS);

    // fc0 (49->128, relu) fused with fc1 (128->16) accumulation
    float acc[C];
    #pragma unroll
    for (int c = 0; c < C; ++c) acc[c] = 0.0f;

    #pragma unroll 2
    for (int k = 0; k < HID; ++k) {
        float hk = fc0_b[k];
        #pragma unroll
        for (int c = 0; c < FC0_IN; ++c)
            hk = fmaf(y[c], fc0_w[k * FC0_IN + c], hk);
        hk = fmaxf(hk, 0.0f);
        #pragma unroll
        for (int c = 0; c < C; ++c)
            acc[c] = fmaf(hk, fc1_w[c * HID + k], acc[c]);
    }

    // sigmoid + residual (fast exp: 16 lanes-worth per thread, VALU-cheap)
    float xo[C];
    #pragma unroll
    for (int c = 0; c < C; ++c) {
        const float s = 1.0f / (1.0f + __expf(-acc[c]));
        xo[c] = y[c] + s;
    }

    // store new state (coalesced float4)
    float4* po = reinterpret_cast<float4*>(x_out + (size_t)cell * C);
    po[0] = make_float4(xo[0], xo[1], xo[2], xo[3]);
    po[1] = make_float4(xo[4], xo[5], xo[6], xo[7]);
    po[2] = make_float4(xo[8], xo[9], xo[10], xo[11]);
    po[3] = make_float4(xo[12], xo[13], xo[14], xo[15]);

    // snapshots: data[b,t] = x wherever acquire_at_step[b,t] == step (step>0)
    if (step > 0) {
        #pragma unroll
        for (int t = 0; t < T; ++t) {
            if (acq[b * T + t] == step) {   // b uniform per block -> scalar load
                float4* ps = reinterpret_cast<float4*>(
                    out + ((((size_t)(b * T + t) * H + h) * W + w) * C));
                ps[0] = make_float4(xo[0], xo[1], xo[2], xo[3]);
                ps[1] = make_float4(xo[4], xo[5], xo[6], xo[7]);
                ps[2] = make_float4(xo[8], xo[9], xo[10], xo[11]);
                ps[3] = make_float4(xo[12], xo[13], xo[14], xo[15]);
            }
        }
    }
}

extern "C" void kernel_launch(void* const* d_in, const int* in_sizes, int n_in,
                              void* d_out, int out_size, void* d_ws, size_t ws_size,
                              hipStream_t stream) {
    const float* inputs = (const float*)d_in[0];
    const int*   acq    = (const int*)d_in[1];
    const float* p0_w   = (const float*)d_in[2];
    const float* p0_b   = (const float*)d_in[3];
    const float* p1_w   = (const float*)d_in[4];
    const float* p1_b   = (const float*)d_in[5];
    const float* fc0_w  = (const float*)d_in[6];
    const float* fc0_b  = (const float*)d_in[7];
    const float* fc1_w  = (const float*)d_in[8];
    float* out = (float*)d_out;

    const size_t state_elems = (size_t)B * H * W * C; // 4,194,304 floats = 16 MB
    float* bufA = (float*)d_ws;
    float* bufB = bufA + state_elems;

    // slots with acquire_at_step==0 must stay zero; d_out is poisoned 0xAA
    hipMemsetAsync(d_out, 0, (size_t)out_size * sizeof(float), stream);

    const int n_cells = B * H * W;          // 262144
    const dim3 grid(n_cells / 256), block(256);

    const float* xin = inputs;
    for (int step = 0; step < NSTEPS; ++step) {
        float* xout = (step & 1) ? bufB : bufA;
        nca_step_kernel<<<grid, block, 0, stream>>>(
            xin, xout, p0_w, p0_b, p1_w, p1_b, fc0_w, fc0_b, fc1_w,
            acq, out, step);
        xin = xout;
    }
}